// Round 3
// baseline (1965.386 us; speedup 1.0000x reference)
//
#include <hip/hip_runtime.h>

#define B_    64
#define S_    48
#define T_    48
#define E_    256
#define H_    512
#define G_    1536   // 3*H
#define VOUT_ 32000
#define NBLK_ 48     // 16 L0-blocks + 32 L1-blocks
#define BH_   (B_ * H_)   // 32768

typedef __attribute__((ext_vector_type(8))) short short8;
typedef __attribute__((ext_vector_type(4))) float f4;

__device__ inline unsigned short f2bf(float f) {
    unsigned u = __float_as_uint(f);
    u += 0x7fffu + ((u >> 16) & 1u);   // RNE
    return (unsigned short)(u >> 16);
}
__device__ inline unsigned pack2(float a, float b) {
    return (unsigned)f2bf(a) | ((unsigned)f2bf(b) << 16);
}

// fast gates: v_exp-based, overflow-safe
__device__ inline float sigf(float x) {
    return __builtin_amdgcn_rcpf(1.f + __expf(-x));
}
__device__ inline float tanh_fast(float x) {
    float e = __expf(-2.f * fabsf(x));           // e in (0,1], never overflows
    float r = (1.f - e) * __builtin_amdgcn_rcpf(1.f + e);
    return copysignf(r, x);
}

// agent-scope (cross-XCD coherent, L2-bypass) accessors — no fences needed
__device__ inline short8 aload16(const unsigned short* p) {
    union { unsigned long long u[2]; short8 s; } f;
    const unsigned long long* q = (const unsigned long long*)p;
    f.u[0] = __hip_atomic_load(q,     __ATOMIC_RELAXED, __HIP_MEMORY_SCOPE_AGENT);
    f.u[1] = __hip_atomic_load(q + 1, __ATOMIC_RELAXED, __HIP_MEMORY_SCOPE_AGENT);
    return f.s;
}
__device__ inline void ast16(unsigned short* p, unsigned short v) {
    __hip_atomic_store(p, v, __ATOMIC_RELAXED, __HIP_MEMORY_SCOPE_AGENT);
}

// ---------------------------------------------------------------- prep
// One launch: zero state+barriers, convert all 9 weight tensors fp32->bf16
// into ONE contiguous destination region.
#define NZ4_  32832    // u32 words to zero: h0b0(64K)+h1b0(64K)+bar(256B)
#define ZBLK_ 129
__global__ __launch_bounds__(256)
void prep(const float* __restrict__ s0, const float* __restrict__ s1,
          const float* __restrict__ s2, const float* __restrict__ s3,
          const float* __restrict__ s4, const float* __restrict__ s5,
          const float* __restrict__ s6, const float* __restrict__ s7,
          const float* __restrict__ s8,
          unsigned short* __restrict__ wt, unsigned* __restrict__ zbase)
{
    const int b = blockIdx.x, tid = threadIdx.x;
    if (b < ZBLK_) {
        int i = b * 256 + tid;
        if (i < NZ4_) zbase[i] = 0u;
        return;
    }
    int i = (b - ZBLK_) * 256 + tid;   // n4 index, grid sized exactly
    const float* src; int off;
    if      (i <   98304) { src = s0; off = 0;       }
    else if (i <  196608) { src = s1; off =  98304;  }
    else if (i <  393216) { src = s2; off = 196608;  }
    else if (i <  589824) { src = s3; off = 393216;  }
    else if (i <  786432) { src = s4; off = 589824;  }
    else if (i <  983040) { src = s5; off = 786432;  }
    else if (i < 1179648) { src = s6; off = 983040;  }
    else if (i < 1376256) { src = s7; off = 1179648; }
    else                  { src = s8; off = 1376256; }
    float4 v = ((const float4*)src)[i - off];
    uint2 o; o.x = pack2(v.x, v.y); o.y = pack2(v.z, v.w);
    ((uint2*)wt)[i] = o;
}

__global__ void zero_out_t0(float* out) {
    int v = blockIdx.x * 256 + threadIdx.x;
    int b = blockIdx.y;
    if (v < VOUT_) out[(size_t)b * T_ * VOUT_ + v] = 0.f;
}

// ---------------------------------------------------------------- MFMA GEMM
// C(M,N) = A(M,K) @ W(N,K)^T + bias   (gi precompute + logits)
__global__ __launch_bounds__(256)
void gemm64(const float* __restrict__ aF,
            const unsigned short* __restrict__ aB,
            const int* __restrict__ idx, int idx_stride,
            const unsigned short* __restrict__ Wb,
            const float* __restrict__ bias,
            float* __restrict__ outF,
            float* __restrict__ outR,
            int N, int K)
{
    __shared__ __align__(16) short As[64][40];
    __shared__ __align__(16) short Ws[64][40];
    const int tid  = threadIdx.x;
    const int m0   = blockIdx.x * 64;
    const int n0   = blockIdx.y * 64;
    const int row  = tid >> 2;
    const int col8 = (tid & 3) * 8;

    const float* apF = nullptr;
    const unsigned short* apB = nullptr;
    {
        int m = m0 + row;
        if (aF) {
            size_t r;
            if (idx) { int tt = m >> 6, b = m & 63; r = (size_t)idx[b * idx_stride + tt]; }
            else     { r = (size_t)m; }
            apF = aF + r * K + col8;
        } else {
            apB = aB + (size_t)m * K + col8;
        }
    }
    const unsigned short* wp = Wb + (size_t)(n0 + row) * K + col8;

    f4 acc[4];
    const f4 zz = {0.f, 0.f, 0.f, 0.f};
    acc[0] = zz; acc[1] = zz; acc[2] = zz; acc[3] = zz;

    const int wv   = tid >> 6;
    const int lane = tid & 63;
    const int quad = lane >> 4;
    const int l16  = lane & 15;

    for (int k0 = 0; k0 < K; k0 += 32) {
        uint4 av;
        if (apF) {
            float4 v0 = *(const float4*)(apF + k0);
            float4 v1 = *(const float4*)(apF + k0 + 4);
            av.x = pack2(v0.x, v0.y);
            av.y = pack2(v0.z, v0.w);
            av.z = pack2(v1.x, v1.y);
            av.w = pack2(v1.z, v1.w);
        } else {
            av = *(const uint4*)(apB + k0);
        }
        uint4 wvv = *(const uint4*)(wp + k0);
        *(uint4*)&As[row][col8] = av;
        *(uint4*)&Ws[row][col8] = wvv;
        __syncthreads();
        short8 afrag = *(const short8*)&As[wv * 16 + l16][quad * 8];
#pragma unroll
        for (int nt = 0; nt < 4; ++nt) {
            short8 bfrag = *(const short8*)&Ws[nt * 16 + l16][quad * 8];
            acc[nt] = __builtin_amdgcn_mfma_f32_16x16x32_bf16(afrag, bfrag, acc[nt], 0, 0, 0);
        }
        __syncthreads();
    }

#pragma unroll
    for (int nt = 0; nt < 4; ++nt) {
#pragma unroll
        for (int r = 0; r < 4; ++r) {
            int mm = m0 + wv * 16 + quad * 4 + r;
            int nn = n0 + nt * 16 + l16;
            float v = acc[nt][r];
            if (bias) v += bias[nn];
            if (outF) {
                outF[(size_t)mm * N + nn] = v;
            } else {
                int tt = mm >> 6, b = mm & 63;             // mm = t*64 + b
                outR[((size_t)b * T_ + tt + 1) * VOUT_ + nn] = v;
            }
        }
    }
}

// ---------------------------------------------------------------- persistent scan
// ONE launch for encoder(48 steps) + decoder(47 steps), 97 slots.
// Blocks 0..15 = L0 (32 cols x 3 gates); blocks 16..47 = L1 (16 cols, 2 phases).
// Slot map: L0 computes enc t=s (s<48), restages LDS at s=48, dec t=s-49 (49..95).
//           L1 computes enc t=s-1 (1..48), restages at s=49, dec t=s-50 (50..96).
// Sync: split monotonic counters, NO threadfence (state uses sc1 atomics):
//   release = per-thread s_waitcnt vmcnt(0); arrive barA(L0)/barB(L1).
//   L0 waits barA>=16s && barB>=32(s-1)  (n0 triple-buffer WAR guard)
//   L1 waits barA>=16s && barB>=32s
// h-state f32 lives in registers for the whole 95-step scan (incl. enc->dec).
__global__ __launch_bounds__(256, 1)
void scan_rnn(const unsigned short* __restrict__ eWhh0,
              const unsigned short* __restrict__ eWih1,
              const unsigned short* __restrict__ eWhh1,
              const unsigned short* __restrict__ dWhh0,
              const unsigned short* __restrict__ dWih1,
              const unsigned short* __restrict__ dWhh1,
              const float* __restrict__ giE, const float* __restrict__ giD,
              const float* __restrict__ ebih1, const float* __restrict__ ebhh0,
              const float* __restrict__ ebhh1,
              const float* __restrict__ dbih1, const float* __restrict__ dbhh0,
              const float* __restrict__ dbhh1,
              unsigned short* __restrict__ h0b0, unsigned short* __restrict__ h0b1,
              unsigned short* __restrict__ h1b0, unsigned short* __restrict__ h1b1,
              unsigned short* __restrict__ n0b,   // 3 buffers, stride BH_
              unsigned short* __restrict__ ys,
              const int* __restrict__ lens,
              unsigned* __restrict__ barA, unsigned* __restrict__ barB)
{
    __shared__ __align__(16) short8 Wl[96][64];   // 96 KiB fragment-major

    const int tid = threadIdx.x, bid = blockIdx.x;
    const int wv = tid >> 6, lane = tid & 63, quad = lane >> 4, l16 = lane & 15;
    const int quad8 = quad * 8;
    const int rowA  = wv * 16 + l16;
    const int mrow  = wv * 16 + quad * 4;
    const bool isL0 = bid < 16;
    const int j0    = isL0 ? bid * 32 : (bid - 16) * 16;
    const f4 zz = {0.f, 0.f, 0.f, 0.f};

    // fragment-major LDS staging (per-block private, conflict-free by layout)
    auto stage = [&](const unsigned short* W0, const unsigned short* W1) {
#pragma unroll 4
        for (int i = 0; i < 24; ++i) {
            const int f = wv * 24 + i;
            const unsigned short* src;
            if (isL0) {
                int kiter = f / 6, rem = f % 6, g = rem >> 1, nt = rem & 1;
                src = W0 + (size_t)(g * H_ + j0 + nt * 16 + l16) * H_ + kiter * 32 + quad8;
            } else {
                int p = f / 48, rem = f % 48, kiter = rem / 3, g = rem % 3;
                const unsigned short* W = p ? W1 : W0;     // W0=Wih1, W1=Whh1
                src = W + (size_t)(g * H_ + j0 + l16) * H_ + kiter * 32 + quad8;
            }
            Wl[f][lane] = *(const short8*)src;
        }
    };

    float b0r[2], b0z[2], b0n[2];
    float b1r = 0.f, b1z = 0.f, b1in = 0.f, b1hn = 0.f;
    auto hoist = [&](const float* bih1, const float* bhh0, const float* bhh1) {
        if (isL0) {
#pragma unroll
            for (int nt = 0; nt < 2; ++nt) {
                const int j = j0 + nt * 16 + l16;
                b0r[nt] = bhh0[j]; b0z[nt] = bhh0[j + H_]; b0n[nt] = bhh0[j + 2 * H_];
            }
        } else {
            const int j = j0 + l16;
            b1r  = bhh1[j] + bih1[j];
            b1z  = bhh1[j + H_] + bih1[j + H_];
            b1in = bih1[j + 2 * H_];
            b1hn = bhh1[j + 2 * H_];
        }
    };

    int lenm[4];
#pragma unroll
    for (int r = 0; r < 4; ++r) lenm[r] = lens[mrow + r];

    float h0r[2][4] = {{0.f,0.f,0.f,0.f},{0.f,0.f,0.f,0.f}};
    float h1r[4]    = {0.f,0.f,0.f,0.f};

    if (isL0) stage(eWhh0, eWhh0); else stage(eWih1, eWhh1);
    hoist(ebih1, ebhh0, ebhh1);
    __syncthreads();

    for (int s = 0; s < 97; ++s) {
        const bool l0c = isL0 && (s < 48 || (s >= 49 && s < 96));
        const bool l1c = (!isL0) && ((s >= 1 && s <= 48) || s >= 50);

        // ---- release + arrive ----
        if (s) {
            asm volatile("s_waitcnt vmcnt(0)" ::: "memory");
            __syncthreads();
            if (tid == 0)
                __hip_atomic_fetch_add(isL0 ? barA : barB, 1u,
                                       __ATOMIC_RELAXED, __HIP_MEMORY_SCOPE_AGENT);
        }

        // ---- hidden under the barrier wait: LDS restage + gi prefetch ----
        if (isL0 && s == 48) { stage(dWhh0, dWhh0); hoist(dbih1, dbhh0, dbhh1); }
        if (!isL0 && s == 49) { stage(dWih1, dWhh1); hoist(dbih1, dbhh0, dbhh1); }

        float gir[2][4], giz[2][4], gin[2][4];
        if (l0c) {
            const float* giT = (s < 48) ? giE + (size_t)s * (B_ * G_)
                                        : giD + (size_t)(s - 49) * (B_ * G_);
#pragma unroll
            for (int nt = 0; nt < 2; ++nt) {
                const int j = j0 + nt * 16 + l16;
#pragma unroll
                for (int r = 0; r < 4; ++r) {
                    const float* g = giT + (size_t)(mrow + r) * G_;
                    gir[nt][r] = g[j];
                    giz[nt][r] = g[j + H_];
                    gin[nt][r] = g[j + 2 * H_];
                }
            }
        }

        // ---- wait ----
        if (s) {
            if (tid == 0) {
                const unsigned tA = 16u * (unsigned)s;
                while (__hip_atomic_load(barA, __ATOMIC_RELAXED,
                                         __HIP_MEMORY_SCOPE_AGENT) < tA)
                    __builtin_amdgcn_s_sleep(1);
                const unsigned tB = isL0 ? (s >= 2 ? 32u * (unsigned)(s - 1) : 0u)
                                         : 32u * (unsigned)s;
                while (__hip_atomic_load(barB, __ATOMIC_RELAXED,
                                         __HIP_MEMORY_SCOPE_AGENT) < tB)
                    __builtin_amdgcn_s_sleep(1);
            }
            __syncthreads();
        }

        if (isL0) {
            if (!l0c) continue;
            const bool enc = (s < 48);
            const int t = enc ? s : s - 49;
            const int a = enc ? s : s - 1;              // L0 active index
            const unsigned short* Ab = (a & 1) ? h0b1 : h0b0;
            unsigned short* hob = (a & 1) ? h0b0 : h0b1;
            unsigned short* nob = n0b + (size_t)(a % 3) * BH_;

            short8 av[16];
#pragma unroll
            for (int k = 0; k < 16; ++k)
                av[k] = aload16(Ab + (size_t)rowA * H_ + k * 32 + quad8);

            f4 acc[4][2];
#pragma unroll
            for (int a2 = 0; a2 < 4; ++a2) { acc[a2][0] = zz; acc[a2][1] = zz; }
#pragma unroll
            for (int k = 0; k < 16; ++k) {
#pragma unroll
                for (int g = 0; g < 3; ++g) {
                    const int ai = (g == 2) ? 3 : g;
#pragma unroll
                    for (int nt = 0; nt < 2; ++nt)
                        acc[ai][nt] = __builtin_amdgcn_mfma_f32_16x16x32_bf16(
                            av[k], Wl[k * 6 + g * 2 + nt][lane], acc[ai][nt], 0, 0, 0);
                }
            }

#pragma unroll
            for (int nt = 0; nt < 2; ++nt) {
                const int j = j0 + nt * 16 + l16;
#pragma unroll
                for (int r = 0; r < 4; ++r) {
                    const int m = mrow + r;
                    float pr = acc[0][nt][r] + b0r[nt] + gir[nt][r];
                    float pz = acc[1][nt][r] + b0z[nt] + giz[nt][r];
                    float hn = acc[3][nt][r] + b0n[nt];
                    float rg = sigf(pr);
                    float zg = sigf(pz);
                    float ng = tanh_fast(gin[nt][r] + rg * hn);
                    float hp = h0r[nt][r];
                    float hnew = (1.f - zg) * ng + zg * hp;
                    ast16(nob + m * H_ + j, f2bf(hnew));      // unmasked n0 -> L1
                    float hw = (enc && t >= lenm[r]) ? hp : hnew;
                    h0r[nt][r] = hw;
                    ast16(hob + m * H_ + j, f2bf(hw));
                }
            }
        } else {
            if (!l1c) continue;
            const bool enc = (s <= 48);
            const int t = enc ? s - 1 : s - 50;
            const int a = enc ? s - 1 : s - 2;          // matching L0 active index
            const unsigned short* xb = n0b + (size_t)(a % 3) * BH_;
            const unsigned short* hb = (a & 1) ? h1b1 : h1b0;
            unsigned short* hob = (a & 1) ? h1b0 : h1b1;

            short8 av0[16], av1[16];
#pragma unroll
            for (int k = 0; k < 16; ++k) {
                av0[k] = aload16(xb + (size_t)rowA * H_ + k * 32 + quad8);
                av1[k] = aload16(hb + (size_t)rowA * H_ + k * 32 + quad8);
            }

            f4 acc[4];
#pragma unroll
            for (int a2 = 0; a2 < 4; ++a2) acc[a2] = zz;
#pragma unroll
            for (int k = 0; k < 16; ++k) {
#pragma unroll
                for (int g = 0; g < 3; ++g) {
                    const int ai = (g == 2) ? 2 : g;    // input n-part
                    acc[ai] = __builtin_amdgcn_mfma_f32_16x16x32_bf16(
                        av0[k], Wl[k * 3 + g][lane], acc[ai], 0, 0, 0);
                }
            }
#pragma unroll
            for (int k = 0; k < 16; ++k) {
#pragma unroll
                for (int g = 0; g < 3; ++g) {
                    const int ai = (g == 2) ? 3 : g;    // hidden n-part
                    acc[ai] = __builtin_amdgcn_mfma_f32_16x16x32_bf16(
                        av1[k], Wl[48 + k * 3 + g][lane], acc[ai], 0, 0, 0);
                }
            }

            const int j = j0 + l16;
#pragma unroll
            for (int r = 0; r < 4; ++r) {
                const int m = mrow + r;
                float pr  = acc[0][r] + b1r;
                float pz  = acc[1][r] + b1z;
                float inn = acc[2][r] + b1in;
                float hn  = acc[3][r] + b1hn;
                float rg = sigf(pr);
                float zg = sigf(pz);
                float ng = tanh_fast(inn + rg * hn);
                float hp = h1r[r];
                float hnew = (1.f - zg) * ng + zg * hp;
                if (!enc) ys[((size_t)t * B_ + m) * H_ + j] = f2bf(hnew);
                float hw = (enc && t >= lenm[r]) ? hp : hnew;
                h1r[r] = hw;
                ast16(hob + m * H_ + j, f2bf(hw));
            }
        }
    }
}

// ---------------------------------------------------------------- launch
extern "C" void kernel_launch(void* const* d_in, const int* in_sizes, int n_in,
                              void* d_out, int out_size, void* d_ws, size_t ws_size,
                              hipStream_t stream)
{
    const int* source  = (const int*)d_in[0];
    const int* target  = (const int*)d_in[1];
    const int* src_len = (const int*)d_in[2];
    const float* enc_emb  = (const float*)d_in[3];
    const float* enc_Wih0 = (const float*)d_in[4];
    const float* enc_Whh0 = (const float*)d_in[5];
    const float* enc_bih0 = (const float*)d_in[6];
    const float* enc_bhh0 = (const float*)d_in[7];
    const float* enc_Wih1 = (const float*)d_in[8];
    const float* enc_Whh1 = (const float*)d_in[9];
    const float* enc_bih1 = (const float*)d_in[10];
    const float* enc_bhh1 = (const float*)d_in[11];
    const float* dec_emb  = (const float*)d_in[12];
    const float* dec_Wih0 = (const float*)d_in[13];
    const float* dec_Whh0 = (const float*)d_in[14];
    const float* dec_bih0 = (const float*)d_in[15];
    const float* dec_bhh0 = (const float*)d_in[16];
    const float* dec_Wih1 = (const float*)d_in[17];
    const float* dec_Whh1 = (const float*)d_in[18];
    const float* dec_bih1 = (const float*)d_in[19];
    const float* dec_bhh1 = (const float*)d_in[20];
    const float* fc_W     = (const float*)d_in[21];
    const float* fc_b     = (const float*)d_in[22];
    float* out = (float*)d_out;

    // ---- workspace layout ----
    char* w = (char*)d_ws;
    unsigned short* h0b0v = (unsigned short*)w; w += (size_t)BH_ * 2;
    unsigned short* h1b0v = (unsigned short*)w; w += (size_t)BH_ * 2;
    unsigned* bar = (unsigned*)w;               w += 256;   // barA=bar, barB=bar+32
    // ^ first NZ4_ u32 words (h0b0,h1b0,bar) zeroed by prep
    unsigned short* h0b1v = (unsigned short*)w; w += (size_t)BH_ * 2;
    unsigned short* h1b1v = (unsigned short*)w; w += (size_t)BH_ * 2;
    unsigned short* n0bv  = (unsigned short*)w; w += (size_t)3 * BH_ * 2;
    float* giE = (float*)w;  w += (size_t)S_ * B_ * G_ * 4;
    float* giD = (float*)w;  w += (size_t)(T_ - 1) * B_ * G_ * 4;
    unsigned short* ysv = (unsigned short*)w; w += (size_t)(T_ - 1) * B_ * H_ * 2;
    unsigned short* wt  = (unsigned short*)w;   // contiguous bf16 weights:
    unsigned short* eWih0b = wt;
    unsigned short* dWih0b = eWih0b + (size_t)G_ * E_;
    unsigned short* eWih1b = dWih0b + (size_t)G_ * E_;
    unsigned short* eWhh0b = eWih1b + (size_t)G_ * H_;
    unsigned short* eWhh1b = eWhh0b + (size_t)G_ * H_;
    unsigned short* dWih1b = eWhh1b + (size_t)G_ * H_;
    unsigned short* dWhh0b = dWih1b + (size_t)G_ * H_;
    unsigned short* dWhh1b = dWhh0b + (size_t)G_ * H_;
    unsigned short* fcWb   = dWhh1b + (size_t)G_ * H_;

    // ---- prep: zero states/barriers + all weight conversions (1 launch) ----
    prep<<<dim3(ZBLK_ + 21376), 256, 0, stream>>>(
        enc_Wih0, dec_Wih0, enc_Wih1, enc_Whh0, enc_Whh1,
        dec_Wih1, dec_Whh0, dec_Whh1, fc_W, wt, (unsigned*)d_ws);
    zero_out_t0<<<dim3((VOUT_ + 255) / 256, B_), 256, 0, stream>>>(out);

    // ---- gi precompute for BOTH phases up front ----
    gemm64<<<dim3(S_ * B_ / 64, G_ / 64), 256, 0, stream>>>(
        enc_emb, nullptr, source, S_, eWih0b, enc_bih0, giE, nullptr, G_, E_);
    gemm64<<<dim3((T_ - 1) * B_ / 64, G_ / 64), 256, 0, stream>>>(
        dec_emb, nullptr, target, T_, dWih0b, dec_bih0, giD, nullptr, G_, E_);

    // ---- single persistent scan: encoder + decoder ----
    scan_rnn<<<NBLK_, 256, 0, stream>>>(
        eWhh0b, eWih1b, eWhh1b, dWhh0b, dWih1b, dWhh1b,
        giE, giD,
        enc_bih1, enc_bhh0, enc_bhh1, dec_bih1, dec_bhh0, dec_bhh1,
        h0b0v, h0b1v, h1b0v, h1b1v, n0bv, ysv, src_len,
        bar, bar + 32);

    // ---- logits = ys @ fc_W^T + fc_b -> out[b, t+1, :] ----
    gemm64<<<dim3((T_ - 1) * B_ / 64, VOUT_ / 64), 256, 0, stream>>>(
        nullptr, ysv, nullptr, 0, fcWb, fc_b, nullptr, out, VOUT_, H_);
}